// Round 1
// baseline (177.723 us; speedup 1.0000x reference)
//
#include <hip/hip_runtime.h>
#include <hip/hip_bf16.h>

#define NB 8
#define NN 2048
#define NF 64      // in features
#define NP 64      // out features per head
#define NH 4
#define NHF 256    // NH*NP

typedef float f32x4 __attribute__((ext_vector_type(4)));
typedef short bf16x8 __attribute__((ext_vector_type(8)));
typedef short s16x4 __attribute__((ext_vector_type(4)));

// f32 -> bf16 bits, round-nearest-even (branchless, no NaN inputs here)
__device__ __forceinline__ short f2bf(float f) {
    unsigned u = __builtin_bit_cast(unsigned, f);
    unsigned r = (u + 0x7fffu + ((u >> 16) & 1u)) >> 16;
    return (short)r;
}

// ---------------------------------------------------------------------------
// Kernel A1: s_out[b,h,n] = x[b,n,:] . (W[h] @ a_out[h]),  same for s_in.
// Exact f32 (algebraic refactor of feats.a). Grid: 256 blocks x 256 thr.
// ---------------------------------------------------------------------------
__global__ __launch_bounds__(256) void gat_scores(
    const float* __restrict__ x, const float* __restrict__ W,
    const float* __restrict__ a_out, const float* __restrict__ a_in,
    float* __restrict__ s_out, float* __restrict__ s_in)
{
    __shared__ float co_lds[NH][NF];
    __shared__ float ci_lds[NH][NF];
    int tid = threadIdx.x;
    int h = tid >> 6, f = tid & 63;
    // c vectors: c[h][f] = sum_o W[h][f][o] * a[h][o]
    {
        float co = 0.f, ci = 0.f;
        const float* wrow = W + (h * NF + f) * NP;
        #pragma unroll 8
        for (int o = 0; o < NP; ++o) {
            float w = wrow[o];
            co = fmaf(w, a_out[h * NP + o], co);
            ci = fmaf(w, a_in[h * NP + o], ci);
        }
        co_lds[h][f] = co;
        ci_lds[h][f] = ci;
    }
    __syncthreads();
    int wid = tid >> 6, lane = tid & 63;
    float cov[NH], civ[NH];
    #pragma unroll
    for (int hh = 0; hh < NH; ++hh) { cov[hh] = co_lds[hh][lane]; civ[hh] = ci_lds[hh][lane]; }
    int base = blockIdx.x * 64 + wid * 16;     // global row in [0, B*N)
    for (int r = 0; r < 16; ++r) {
        int gn = base + r;
        float xv = x[(size_t)gn * NF + lane];
        #pragma unroll
        for (int hh = 0; hh < NH; ++hh) {
            float vo = xv * cov[hh];
            float vi = xv * civ[hh];
            #pragma unroll
            for (int s2 = 1; s2 < 64; s2 <<= 1) {
                vo += __shfl_xor(vo, s2, 64);
                vi += __shfl_xor(vi, s2, 64);
            }
            if (lane == 0) {
                int b = gn >> 11, n = gn & (NN - 1);
                s_out[((size_t)b * NH + hh) * NN + n] = vo;
                s_in [((size_t)b * NH + hh) * NN + n] = vi;
            }
        }
    }
}

// ---------------------------------------------------------------------------
// Kernel A2: featsT[b,h,o,n] (bf16) = (x[b] @ W[h])^T via MFMA 16x16x32 bf16.
// Grid: B*H*(N/64) = 1024 blocks x 256 thr (4 waves of 16 rows each).
// ---------------------------------------------------------------------------
__global__ __launch_bounds__(256) void gat_feats(
    const float* __restrict__ x, const float* __restrict__ W,
    short* __restrict__ featsT)
{
    int blk = blockIdx.x;
    int nb = blk & 31;           // N/64 = 32
    int h  = (blk >> 5) & 3;
    int b  = blk >> 7;
    int tid = threadIdx.x, wid = tid >> 6, lane = tid & 63;
    int n0 = nb * 64 + wid * 16;
    int rA = lane & 15, g = lane >> 4;

    // A fragments: rows of x (bf16), K = 64 -> 2 k-steps of 32
    bf16x8 af[2];
    #pragma unroll
    for (int kk = 0; kk < 2; ++kk) {
        const float* xp = x + ((size_t)(b * NN) + n0 + rA) * NF + kk * 32 + g * 8;
        f32x4 x0 = *(const f32x4*)xp;
        f32x4 x1 = *(const f32x4*)(xp + 4);
        #pragma unroll
        for (int e = 0; e < 4; ++e) {
            af[kk][e]     = f2bf(x0[e]);
            af[kk][e + 4] = f2bf(x1[e]);
        }
    }
    f32x4 acc[4] = {};
    #pragma unroll
    for (int o = 0; o < 4; ++o) {
        #pragma unroll
        for (int kk = 0; kk < 2; ++kk) {
            bf16x8 bfv;
            #pragma unroll
            for (int e = 0; e < 8; ++e) {
                float wv = W[((size_t)h * NF + kk * 32 + g * 8 + e) * NP + o * 16 + rA];
                bfv[e] = f2bf(wv);
            }
            acc[o] = __builtin_amdgcn_mfma_f32_16x16x32_bf16(af[kk], bfv, acc[o], 0, 0, 0);
        }
    }
    // D layout: col = lane&15 (=o col), row = (lane>>4)*4 + reg (=n)
    #pragma unroll
    for (int o = 0; o < 4; ++o) {
        s16x4 pk;
        pk[0] = f2bf(acc[o][0]);
        pk[1] = f2bf(acc[o][1]);
        pk[2] = f2bf(acc[o][2]);
        pk[3] = f2bf(acc[o][3]);
        *(s16x4*)(featsT + ((size_t)((b * NH + h) * NP) + o * 16 + rA) * NN + n0 + g * 4) = pk;
    }
}

// ---------------------------------------------------------------------------
// Kernel B: fused masked-softmax attention + PV.
// Grid: B*(N/64) = 256 blocks x 512 thr (8 waves: 4 heads x 2 i-halves).
// No max-tracking softmax (scores bounded; masked -> exp underflows to 0).
// ---------------------------------------------------------------------------
__global__ __launch_bounds__(512, 2) void gat_attn(
    const float* __restrict__ mask,    // [B,N,N]
    const float* __restrict__ adj,     // [B,N,N]
    const short* __restrict__ featsT,  // [B,H,FP,N] bf16 bits
    const float* __restrict__ s_out,   // [B,H,N]
    const float* __restrict__ s_in,    // [B,H,N]
    const float* __restrict__ biases,  // [H,FP]
    float* __restrict__ out)           // [B,N,H*FP]
{
    const int LDM = 36;  // padded row stride (floats) for mask+adj tile
    __shared__ __align__(16) float si_lds[NH][NN];        // 32 KB
    __shared__ __align__(16) float ma_lds[2][64][LDM];    // 18 KB

    int blk = blockIdx.x;
    int b  = blk >> 5;            // 32 i-blocks per batch
    int ib = blk & 31;
    int i_base = ib * 64;
    int tid = threadIdx.x;
    int wid = tid >> 6;
    int lane = tid & 63;
    int h = wid & 3;
    int ihalf = wid >> 2;
    int colg = lane & 15;
    int jb = (lane >> 4) * 8;     // local k(=j) base for MFMA fragments

    // stage s_in for all heads into LDS (H*N = 8192 floats)
    {
        const f32x4* src = (const f32x4*)(s_in + (size_t)b * NH * NN);
        f32x4* dst = (f32x4*)(&si_lds[0][0]);
        #pragma unroll
        for (int k = 0; k < 4; ++k) dst[tid + k * 512] = src[tid + k * 512];
    }
    // this wave's outgoing scores (one per i-subtile row class)
    float so0 = s_out[((size_t)b * NH + h) * NN + i_base + ihalf * 32 + colg];
    float so1 = s_out[((size_t)b * NH + h) * NN + i_base + ihalf * 32 + 16 + colg];

    // mask+adj tile loader: each thread owns one float4 of the 64x32 tile
    int li = tid >> 3;
    int lj = (tid & 7) * 4;
    const float* mrow = mask + ((size_t)b * NN + i_base + li) * NN + lj;
    const float* arow = adj  + ((size_t)b * NN + i_base + li) * NN + lj;

    // prologue: chunk 0 into buffer 0
    {
        f32x4 m4 = *(const f32x4*)(mrow);
        f32x4 a4 = *(const f32x4*)(arow);
        f32x4 s4 = m4 + a4;
        *(f32x4*)(&ma_lds[0][li][lj]) = s4;
    }
    __syncthreads();

    f32x4 acc[2][4] = {};
    float dsum[2] = {0.f, 0.f};

    const short* vbase0 = featsT + (size_t)((b * NH + h) * NP) * NN;
    const int NC = NN / 32;   // 64 chunks

    for (int c = 0; c < NC; ++c) {
        int cur = c & 1;
        int j0 = c * 32;
        // prefetch next chunk into registers (issued early, consumed late)
        f32x4 m4n, a4n;
        if (c + 1 < NC) {
            m4n = *(const f32x4*)(mrow + (c + 1) * 32);
            a4n = *(const f32x4*)(arow + (c + 1) * 32);
        }
        // V fragments (B-operand): contiguous 16B from featsT
        bf16x8 vf[4];
        const short* vb = vbase0 + j0 + jb;
        #pragma unroll
        for (int o = 0; o < 4; ++o)
            vf[o] = *(const bf16x8*)(vb + (size_t)(o * 16 + colg) * NN);
        // incoming scores for this chunk's 8 j's
        f32x4 siA = *(const f32x4*)(&si_lds[h][j0 + jb]);
        f32x4 siB = *(const f32x4*)(&si_lds[h][j0 + jb + 4]);

        #pragma unroll
        for (int s = 0; s < 2; ++s) {
            int il = ihalf * 32 + s * 16 + colg;
            f32x4 maA = *(const f32x4*)(&ma_lds[cur][il][jb]);
            f32x4 maB = *(const f32x4*)(&ma_lds[cur][il][jb + 4]);
            float so = s ? so1 : so0;
            bf16x8 af;
            float ds = 0.f;
            #pragma unroll
            for (int e = 0; e < 8; ++e) {
                float sv = (e < 4) ? siA[e] : siB[e - 4];
                float mv = (e < 4) ? maA[e] : maB[e - 4];
                float t = so + sv;
                float lr = fmaxf(t, 0.2f * t);        // leaky_relu(0.2)
                float p = __expf(lr + mv);            // masked -> exp(-1e9) = 0
                ds += p;
                af[e] = f2bf(p);
            }
            dsum[s] += ds;
            #pragma unroll
            for (int o = 0; o < 4; ++o)
                acc[s][o] = __builtin_amdgcn_mfma_f32_16x16x32_bf16(af, vf[o], acc[s][o], 0, 0, 0);
        }
        // write next chunk into the other buffer (after compute; waits on loads)
        if (c + 1 < NC) {
            f32x4 sn = m4n + a4n;
            *(f32x4*)(&ma_lds[cur ^ 1][li][lj]) = sn;
        }
        __syncthreads();
    }

    // row denominators: sum across the 4 j-groups -> all lanes hold denom[row=lane&15]
    #pragma unroll
    for (int s = 0; s < 2; ++s) {
        dsum[s] += __shfl_xor(dsum[s], 16, 64);
        dsum[s] += __shfl_xor(dsum[s], 32, 64);
    }
    int rowg = (lane >> 4) * 4;
    float bias_v[4];
    #pragma unroll
    for (int o = 0; o < 4; ++o) bias_v[o] = biases[h * NP + o * 16 + colg];

    #pragma unroll
    for (int s = 0; s < 2; ++s) {
        #pragma unroll
        for (int reg = 0; reg < 4; ++reg) {
            float dd = __shfl(dsum[s], rowg + reg, 64);   // denom for D-row
            float rcp = 1.0f / dd;
            int n = i_base + ihalf * 32 + s * 16 + rowg + reg;
            float* orow = out + ((size_t)b * NN + n) * NHF + h * NP;
            #pragma unroll
            for (int o = 0; o < 4; ++o) {
                float y = acc[s][o][reg] * rcp + bias_v[o];
                y = (y > 0.f) ? y : (__expf(y) - 1.0f);   // ELU
                orow[o * 16 + colg] = y;
            }
        }
    }
}

extern "C" void kernel_launch(void* const* d_in, const int* in_sizes, int n_in,
                              void* d_out, int out_size, void* d_ws, size_t ws_size,
                              hipStream_t stream) {
    const float* x      = (const float*)d_in[0];  // node_feats [B,N,F]
    const float* adj    = (const float*)d_in[1];  // adjacency  [B,N,N]
    const float* mask   = (const float*)d_in[2];  // attn_mask  [B,N,N]
    const float* W      = (const float*)d_in[3];  // kernels    [H,F,FP]
    const float* biases = (const float*)d_in[4];  // [H,FP]
    const float* a_out  = (const float*)d_in[5];  // [H,FP]
    const float* a_in   = (const float*)d_in[6];  // [H,FP]
    float* out = (float*)d_out;

    char* ws = (char*)d_ws;
    short* featsT = (short*)ws;                                // 8 MB bf16 [B,H,FP,N]
    float* s_out  = (float*)(ws + 8388608);                    // 256 KB
    float* s_in   = (float*)(ws + 8388608 + 262144);           // 256 KB

    gat_scores<<<256, 256, 0, stream>>>(x, W, a_out, a_in, s_out, s_in);
    gat_feats<<<NB * NH * (NN / 64), 256, 0, stream>>>(x, W, featsT);
    gat_attn<<<NB * (NN / 64), 512, 0, stream>>>(mask, adj, featsT, s_out, s_in, biases, out);
}